// Round 18
// baseline (150.867 us; speedup 1.0000x reference)
//
#include <hip/hip_runtime.h>
#include <hip/hip_bf16.h>
#include <stdint.h>

typedef __attribute__((ext_vector_type(8))) short bf16x8_t;
typedef __attribute__((ext_vector_type(4))) float f32x4_t;
typedef unsigned int u32;
typedef unsigned short u16;
typedef u32 __attribute__((address_space(3))) lds_u32;
typedef u32 __attribute__((address_space(1))) gbl_u32;

#define NUM_H 12
#define NTOK 196
#define NBATCH 64
#define CDIM 768
#define VTS 224    // V^T global token stride
#define VLS 232    // V^T LDS token stride (bank-friendly)
#define RPS 208    // rpb transposed pad (cols and qr)
#define LOG2E 1.44269504f

__device__ __forceinline__ u16 f2bf(float f) {
    u32 u = __float_as_uint(f);
    u32 r = u + 0x7FFFu + ((u >> 16) & 1u);
    return (u16)(r >> 16);
}

// ---- prep: fp32->bf16 convert (3 arrays) + rpb expand, one launch ----
__global__ void prep_kernel(const float* __restrict__ a, u16* __restrict__ oa, int na4,
                            const float* __restrict__ b, u16* __restrict__ ob, int nb4,
                            const float* __restrict__ c, u16* __restrict__ oc, int nc4,
                            const float* __restrict__ table, const int* __restrict__ idx,
                            float* __restrict__ rpbt) {
    // rpb part: [729][12] -> [12][208 col][208 qr], log2-domain, pads -1e30
    int ij = blockIdx.x * 256 + threadIdx.x;
    if (ij < RPS * RPS) {
        const int qr = ij / RPS, col = ij - qr * RPS;
        const bool pad = (qr >= NTOK) | (col >= NTOK);
        const int rp = pad ? 0 : idx[qr * NTOK + col];
        #pragma unroll
        for (int h = 0; h < NUM_H; h++)
            rpbt[((size_t)h * RPS + col) * RPS + qr] =
                pad ? -1e30f : table[rp * NUM_H + h] * LOG2E;
    }
    // cvt part: grid-stride
    const int total = na4 + nb4 + nc4;
    for (int i = blockIdx.x * blockDim.x + threadIdx.x; i < total; i += gridDim.x * blockDim.x) {
        const float* src;
        u16* dst;
        int j = i;
        if (j < na4) { src = a; dst = oa; }
        else if ((j -= na4) < nb4) { src = b; dst = ob; }
        else { j -= nb4; src = c; dst = oc; }
        float4 v = ((const float4*)src)[j];
        ushort4 o;
        o.x = f2bf(v.x); o.y = f2bf(v.y); o.z = f2bf(v.z); o.w = f2bf(v.w);
        ((ushort4*)dst)[j] = o;
    }
}

// ---------------- GEMM: C[M,N] = A[M,K] @ W[N,K]^T  (bf16 in, epilogue per mode) ----
// 2-phase K-step, triple-buffered LDS, counted vmcnt, 2-ahead DMA (r17, verified).
// BN=256: QKV (72KB, 2 blk/CU, vmcnt(6)). BN=128: proj (48KB, 3 blk/CU, vmcnt(4)).
template <int BN>
__global__ __launch_bounds__(256, BN == 256 ? 2 : 3) void gemm_kernel(
    const u16* __restrict__ A, const u16* __restrict__ W, int K, int mode,
    const float* __restrict__ bias_q, const float* __restrict__ bias_v,
    u16* __restrict__ oq, u16* __restrict__ ok, u16* __restrict__ ovt,
    const float* __restrict__ pbias, float* __restrict__ of) {
    constexpr int NBT = BN / 32;        // n-tiles (16 wide) per wave
    constexpr int HBT = NBT / 2;        // per phase
    constexpr int BOFF = 4096;          // A area in u16
    constexpr int BC = BN / 128;        // B chunks per wave per phase
    __shared__ __align__(16) u16 lds[3][BOFF + BN * 32];
    const int tid = threadIdx.x;
    const int wave = tid >> 6, lane = tid & 63;
    const int wr = wave >> 1, wc = wave & 1; // 2x2 wave grid
    const int bid = blockIdx.x;
    const int xcd = bid & 7, i = bid >> 3;
    const int i13 = i / 13;
    const int bm = xcd * 13 + (i - i13 * 13);
    const int bn = i13;
    if (bm >= 98) return; // pad blocks (uniform per block, before any barrier)

    f32x4_t acc[4][NBT];
    #pragma unroll
    for (int ii = 0; ii < 4; ii++)
        #pragma unroll
        for (int jj = 0; jj < NBT; jj++) acc[ii][jj] = f32x4_t{0.f, 0.f, 0.f, 0.f};

    // phase0 stage: A (2 chunks) + first half of B (BC chunks)
    auto stageA = [&](int buf, int kt) {
        const int k0 = kt * 32;
        const int su = (lane & 3) ^ ((lane >> 2) & 3) ^ ((lane >> 4) & 3);
        #pragma unroll
        for (int c2 = 0; c2 < 2; c2++) {
            const int c = wave * 2 + c2;
            const int row = bm * 128 + c * 16 + (lane >> 2);
            const u16* src = A + (size_t)row * K + k0 + su * 8;
            __builtin_amdgcn_global_load_lds((gbl_u32*)src, (lds_u32*)&lds[buf][c * 512], 16, 0, 0);
        }
        #pragma unroll
        for (int c2 = 0; c2 < BC; c2++) {
            const int c = wave * (BN / 64) + c2;
            const int row = bn * BN + c * 16 + (lane >> 2);
            const u16* src = W + (size_t)row * K + k0 + su * 8;
            __builtin_amdgcn_global_load_lds((gbl_u32*)src, (lds_u32*)&lds[buf][BOFF + c * 512], 16, 0, 0);
        }
    };
    // phase1 stage: second half of B (BC chunks)
    auto stageB = [&](int buf, int kt) {
        const int k0 = kt * 32;
        const int su = (lane & 3) ^ ((lane >> 2) & 3) ^ ((lane >> 4) & 3);
        #pragma unroll
        for (int c2 = 0; c2 < BC; c2++) {
            const int c = wave * (BN / 64) + BC + c2;
            const int row = bn * BN + c * 16 + (lane >> 2);
            const u16* src = W + (size_t)row * K + k0 + su * 8;
            __builtin_amdgcn_global_load_lds((gbl_u32*)src, (lds_u32*)&lds[buf][BOFF + c * 512], 16, 0, 0);
        }
    };

    const int NKT = K >> 5; // 24
    stageA(0, 0); stageB(0, 0);
    if (NKT > 1) { stageA(1, 1); stageB(1, 1); }
    #pragma unroll 3
    for (int kt = 0; kt < NKT; ++kt) {
        const int buf = kt % 3;
        if (kt + 1 < NKT) {
            if constexpr (BN == 256) asm volatile("s_waitcnt vmcnt(6)" ::: "memory");
            else                     asm volatile("s_waitcnt vmcnt(4)" ::: "memory");
        } else {
            asm volatile("s_waitcnt vmcnt(0)" ::: "memory");
        }
        __builtin_amdgcn_s_barrier(); // buf(kt) resident; buf reuse safe
        // ---- phase 0 ----
        if (kt + 2 < NKT) stageA((kt + 2) % 3, kt + 2);
        bf16x8_t af[4], bfr[NBT];
        #pragma unroll
        for (int mt = 0; mt < 4; mt++) {
            const int r = wr * 64 + mt * 16 + (lane & 15);
            const int u = (lane >> 4) ^ (r & 3) ^ ((r >> 2) & 3);
            af[mt] = *(const bf16x8_t*)&lds[buf][r * 32 + u * 8];
        }
        #pragma unroll
        for (int nt = 0; nt < HBT; nt++) {
            const int r = wc * (BN / 2) + nt * 16 + (lane & 15);
            const int u = (lane >> 4) ^ (r & 3) ^ ((r >> 2) & 3);
            bfr[nt] = *(const bf16x8_t*)&lds[buf][BOFF + r * 32 + u * 8];
        }
        __builtin_amdgcn_s_setprio(1);
        #pragma unroll
        for (int mt = 0; mt < 4; mt++)
            #pragma unroll
            for (int nt = 0; nt < HBT; nt++)
                acc[mt][nt] = __builtin_amdgcn_mfma_f32_16x16x32_bf16(af[mt], bfr[nt], acc[mt][nt], 0, 0, 0);
        __builtin_amdgcn_s_setprio(0);
        __builtin_amdgcn_s_barrier(); // phase boundary (role-split only)
        // ---- phase 1 ----
        if (kt + 2 < NKT) stageB((kt + 2) % 3, kt + 2);
        #pragma unroll
        for (int nt = HBT; nt < NBT; nt++) {
            const int r = wc * (BN / 2) + nt * 16 + (lane & 15);
            const int u = (lane >> 4) ^ (r & 3) ^ ((r >> 2) & 3);
            bfr[nt] = *(const bf16x8_t*)&lds[buf][BOFF + r * 32 + u * 8];
        }
        __builtin_amdgcn_s_setprio(1);
        #pragma unroll
        for (int mt = 0; mt < 4; mt++)
            #pragma unroll
            for (int nt = HBT; nt < NBT; nt++)
                acc[mt][nt] = __builtin_amdgcn_mfma_f32_16x16x32_bf16(af[mt], bfr[nt], acc[mt][nt], 0, 0, 0);
        __builtin_amdgcn_s_setprio(0);
    }

    const int g = lane >> 4, lc = lane & 15;
    if (mode == 0) {
        if constexpr (BN == 256) {
            const int n_base = bn * 256 + wc * 128; // single qkv region (768 = 3*256)
            const int which = n_base / CDIM;
            const int rem0 = n_base - which * CDIM;
            if (which == 2) {
                #pragma unroll
                for (int nt = 0; nt < 8; nt++) {
                    const int rem = rem0 + nt * 16 + lc;
                    const int hh = rem >> 6, d = rem & 63;
                    const float bias = bias_v[rem];
                    #pragma unroll
                    for (int mt = 0; mt < 4; mt++) {
                        const int m0 = bm * 128 + wr * 64 + mt * 16 + 4 * g;
                        const int bb = m0 / NTOK, t0 = m0 - bb * NTOK; // r=0..3 in-row (196%4==0)
                        ushort4 vv;
                        vv.x = f2bf(acc[mt][nt][0] + bias);
                        vv.y = f2bf(acc[mt][nt][1] + bias);
                        vv.z = f2bf(acc[mt][nt][2] + bias);
                        vv.w = f2bf(acc[mt][nt][3] + bias);
                        *(ushort4*)&ovt[(((size_t)bb * NUM_H + hh) * 64 + d) * VTS + t0] = vv;
                    }
                }
            } else {
                // q/k: LDS-bounce wave's 64x128 tile, then 16 coalesced bf16x8 stores.
                __builtin_amdgcn_s_barrier(); // bounce area overlaps K-loop bufs
                u16* tile = ((u16*)lds) + wave * 8192; // 16KB per wave
                const float scale = (which == 0) ? 0.125f * LOG2E : 1.f;
                #pragma unroll
                for (int nt = 0; nt < 8; nt++) {
                    const int rem = rem0 + nt * 16 + lc;
                    const float bias = (which == 0) ? bias_q[rem] : 0.f;
                    const int nl = nt * 16 + lc;
                    #pragma unroll
                    for (int mt = 0; mt < 4; mt++) {
                        #pragma unroll
                        for (int r = 0; r < 4; r++) {
                            const int ml = mt * 16 + 4 * g + r;
                            const int nsw = (nl & 7) | ((((nl >> 3) ^ (ml & 15)) & 15) << 3);
                            tile[ml * 128 + nsw] = f2bf((acc[mt][nt][r] + bias) * scale);
                        }
                    }
                }
                asm volatile("s_waitcnt lgkmcnt(0)" ::: "memory");
                u16* dst = (which == 0) ? oq : ok;
                const int hh0 = rem0 >> 6;
                #pragma unroll
                for (int it = 0; it < 16; it++) {
                    const int ml = it * 4 + (lane >> 4);
                    const int u = lane & 15;
                    const int usw = u ^ (ml & 15);
                    bf16x8_t v = *(const bf16x8_t*)&tile[ml * 128 + usw * 8];
                    const int mg = bm * 128 + wr * 64 + ml;
                    const int bb = mg / NTOK, t = mg - bb * NTOK;
                    const int hh = hh0 + (u >> 3), d0 = (u & 7) * 8;
                    *(bf16x8_t*)&dst[(((size_t)bb * NUM_H + hh) * NTOK + t) * 64 + d0] = v;
                }
            }
        }
    } else {
        #pragma unroll
        for (int mt = 0; mt < 4; mt++) {
            #pragma unroll
            for (int r = 0; r < 4; r++) {
                const int m = bm * 128 + wr * 64 + mt * 16 + 4 * g + r;
                #pragma unroll
                for (int nt = 0; nt < NBT; nt++) {
                    const int n = bn * BN + wc * (BN / 2) + nt * 16 + lc;
                    of[(size_t)m * CDIM + n] = acc[mt][nt][r] + pbias[n];
                }
            }
        }
    }
}

// ---------------- attention: one block per (b,h), 8 WAVES (r18) ----------------
// r17 showed attn Occ ~18% with a 4-tile per-block critical path. 8 waves/block:
// per-block path = staging + 2 tiles (waves 0-4: qt w,w+8; 5-7: one tile), and
// residency doubles to 4 waves/SIMD (2 blocks/CU, LDS 72.7KB). Per-wave code is
// identical to r17 (VGPR ~112 <= cap 128 at bounds(512,4) -> no spill expected).
__global__ __launch_bounds__(512, 4) void attn_kernel(
    const u16* __restrict__ Q, const u16* __restrict__ Kg, const u16* __restrict__ Vt,
    const float* __restrict__ rpbt, u16* __restrict__ O) {
    __shared__ __align__(16) u16 Ks[208 * 64];   // 26624 B, swizzled rows
    __shared__ __align__(16) u16 Vs[64 * VLS];   // 29696 B = 29 chunks
    __shared__ __align__(16) u16 Ps[8][16 * 64]; // per-wave P transpose buffer (16KB)
    const int lane = threadIdx.x & 63, wave = threadIdx.x >> 6;
    const int x = blockIdx.x & 7, j = blockIdx.x >> 3;
    const int j12 = j / 12;
    const int b = 8 * x + j12;
    const int h = j - 12 * j12;
    const int bh = b * NUM_H + h;
    const u16* Qb = Q + (size_t)bh * NTOK * 64;
    const u16* Kb = Kg + (size_t)bh * NTOK * 64;
    const u16* Vgb = Vt + (size_t)bh * 64 * VTS;
    const int g = lane >> 4, lc = lane & 15;

    // DMA staging: 26 K-chunks then 29 V-chunks of 1KB, round-robin over 8 waves.
    // Per-wave c ascending -> all K issues precede V issues.
    for (int c = wave; c < 26 + 29; c += 8) {
        if (c < 26) {
            const int row = c * 8 + (lane >> 3);
            const int u = lane & 7;
            const int srow = (row < NTOK) ? row : (NTOK - 1);
            const u16* src = Kb + srow * 64 + ((u ^ (row & 7)) << 3);
            __builtin_amdgcn_global_load_lds((gbl_u32*)src, (lds_u32*)&Ks[c * 512], 16, 0, 0);
        } else {
            const int p = (c - 26) * 1024 + lane * 16;
            const int d = p / (VLS * 2);
            const int off = p - d * (VLS * 2);
            const u16* src = (off < VTS * 2) ? (Vgb + d * VTS + (off >> 1)) : Vgb;
            __builtin_amdgcn_global_load_lds((gbl_u32*)src, (lds_u32*)((char*)Vs + (c - 26) * 1024), 16, 0, 0);
        }
    }
    // Per-wave V-chunk counts: waves {0,1,7}: 3 outstanding V; waves 2-6: 4.
    // Waiting down to that count leaves only V in flight => all K landed.
    if (wave >= 2 && wave <= 6) asm volatile("s_waitcnt vmcnt(4)" ::: "memory");
    else                        asm volatile("s_waitcnt vmcnt(3)" ::: "memory");
    __builtin_amdgcn_s_barrier(); // all waves' K resident; V still in flight

    bool vpending = true;
    for (int qt = wave; qt < 13; qt += 8) {
        const float* rpbc = rpbt + ((size_t)h * RPS + lc) * RPS + qt * 16 + 4 * g;
        bf16x8_t qf[2];
        const int qrow_f = qt * 16 + lc;
        #pragma unroll
        for (int kk = 0; kk < 2; kk++) {
            if (qrow_f < NTOK) qf[kk] = *(const bf16x8_t*)(Qb + qrow_f * 64 + kk * 32 + g * 8);
            else qf[kk] = bf16x8_t{0, 0, 0, 0, 0, 0, 0, 0};
        }
        float4 rp13[13];
        #pragma unroll
        for (int nt = 0; nt < 13; nt++) rp13[nt] = *(const float4*)(rpbc + nt * 16 * RPS);
        f32x4_t s[13];
        #pragma unroll
        for (int nt = 0; nt < 13; nt++) s[nt] = f32x4_t{0.f, 0.f, 0.f, 0.f};
        #pragma unroll
        for (int nt = 0; nt < 13; nt++) {
            #pragma unroll
            for (int kk = 0; kk < 2; kk++) {
                const int kr = nt * 16 + lc;
                const int u = (kk * 4 + g) ^ (kr & 7);
                bf16x8_t kf = *(const bf16x8_t*)&Ks[kr * 64 + u * 8];
                s[nt] = __builtin_amdgcn_mfma_f32_16x16x32_bf16(qf[kk], kf, s[nt], 0, 0, 0);
            }
        }
        // + rpb (pads carry -1e30: maskless), row max — exp2 domain
        float mx[4] = {-3e38f, -3e38f, -3e38f, -3e38f};
        #pragma unroll
        for (int nt = 0; nt < 13; nt++) {
            const float rpv[4] = {rp13[nt].x, rp13[nt].y, rp13[nt].z, rp13[nt].w};
            #pragma unroll
            for (int r = 0; r < 4; r++) {
                const float v = s[nt][r] + rpv[r];
                s[nt][r] = v;
                mx[r] = fmaxf(mx[r], v);
            }
        }
        #pragma unroll
        for (int r = 0; r < 4; r++) {
            mx[r] = fmaxf(mx[r], __shfl_xor(mx[r], 1));
            mx[r] = fmaxf(mx[r], __shfl_xor(mx[r], 2));
            mx[r] = fmaxf(mx[r], __shfl_xor(mx[r], 4));
            mx[r] = fmaxf(mx[r], __shfl_xor(mx[r], 8));
        }
        float sm[4] = {0.f, 0.f, 0.f, 0.f};
        #pragma unroll
        for (int nt = 0; nt < 13; nt++)
            #pragma unroll
            for (int r = 0; r < 4; r++) {
                float p = exp2f(s[nt][r] - mx[r]);
                s[nt][r] = p;
                sm[r] += p;
            }
        float inv[4];
        #pragma unroll
        for (int r = 0; r < 4; r++) {
            sm[r] += __shfl_xor(sm[r], 1);
            sm[r] += __shfl_xor(sm[r], 2);
            sm[r] += __shfl_xor(sm[r], 4);
            sm[r] += __shfl_xor(sm[r], 8);
            inv[r] = 1.f / sm[r];
        }

        if (vpending) { // V landed? drain once before the first PV (all 8 waves rendezvous)
            asm volatile("s_waitcnt vmcnt(0)" ::: "memory");
            __builtin_amdgcn_s_barrier();
            vpending = false;
        }

        f32x4_t o4[4];
        #pragma unroll
        for (int dt = 0; dt < 4; dt++) o4[dt] = f32x4_t{0.f, 0.f, 0.f, 0.f};
        for (int kc = 0; kc < 4; kc++) {
            #pragma unroll
            for (int ntl = 0; ntl < 4; ntl++) {
                const int nt = kc * 4 + ntl;
                const int kl = ntl * 16 + lc;
                #pragma unroll
                for (int r = 0; r < 4; r++) {
                    const int rr = 4 * g + r;
                    u16 pv = 0;
                    if (nt < 13) pv = f2bf(s[nt][r]);
                    Ps[wave][rr * 64 + (((kl >> 3) ^ (rr & 7)) << 3) + (kl & 7)] = pv;
                }
            }
            asm volatile("s_waitcnt lgkmcnt(0)" ::: "memory");
            const int nsteps = (kc < 3) ? 2 : 1;
            for (int ks = 0; ks < nsteps; ks++) {
                const int rr = lc;
                const int u = (ks * 4 + g) ^ (rr & 7);
                bf16x8_t pf = *(const bf16x8_t*)&Ps[wave][rr * 64 + u * 8];
                #pragma unroll
                for (int dt = 0; dt < 4; dt++) {
                    const int dcol = dt * 16 + lc;
                    const int kb = kc * 64 + ks * 32 + g * 8;
                    bf16x8_t vf = *(const bf16x8_t*)&Vs[dcol * VLS + kb];
                    o4[dt] = __builtin_amdgcn_mfma_f32_16x16x32_bf16(pf, vf, o4[dt], 0, 0, 0);
                }
            }
            asm volatile("" ::: "memory");
        }
        #pragma unroll
        for (int dt = 0; dt < 4; dt++)
            #pragma unroll
            for (int r = 0; r < 4; r++) {
                const int qr = qt * 16 + 4 * g + r;
                if (qr < NTOK)
                    O[((size_t)b * NTOK + qr) * CDIM + h * 64 + dt * 16 + lc] = f2bf(o4[dt][r] * inv[r]);
            }
    }
}

extern "C" void kernel_launch(void* const* d_in, const int* in_sizes, int n_in,
                              void* d_out, int out_size, void* d_ws, size_t ws_size,
                              hipStream_t stream) {
    const float* x = (const float*)d_in[0];
    const float* qkvw = (const float*)d_in[1];
    const float* qb = (const float*)d_in[2];
    const float* vb = (const float*)d_in[3];
    const float* rpbt = (const float*)d_in[4];
    const int* rpi = (const int*)d_in[5];
    const float* pw = (const float*)d_in[6];
    const float* pb = (const float*)d_in[7];
    float* out = (float*)d_out;

    char* ws = (char*)d_ws;
    size_t off = 0;
    auto alloc = [&](size_t bytes) {
        void* p = ws + off;
        off += (bytes + 255) & ~(size_t)255;
        return p;
    };
    const size_t MROWS = 12544; // 64*196
    u16* xbf = (u16*)alloc(MROWS * 768 * 2);
    u16* wbf = (u16*)alloc((size_t)2304 * 768 * 2);
    u16* pwbf = (u16*)alloc((size_t)768 * 768 * 2);
    u16* qws = (u16*)alloc(MROWS * 768 * 2);
    u16* kws = (u16*)alloc(MROWS * 768 * 2);
    u16* vtws = (u16*)alloc((size_t)768 * 64 * VTS * 2 + 256); // V^T [bh][64][VTS] (+slack)
    u16* aout = (u16*)alloc(MROWS * 768 * 2);
    float* rpbm = (float*)alloc((size_t)NUM_H * RPS * RPS * 4 + 256); // [h][col][qr], log2-domain, pads -1e30

    prep_kernel<<<2048, 256, 0, stream>>>(x, xbf, (12544 * 768) / 4,
                                          qkvw, wbf, (2304 * 768) / 4,
                                          pw, pwbf, (768 * 768) / 4,
                                          rpbt, rpi, rpbm);
    // XCD-swizzled 1D grids: 8 XCDs * 13 bm-strip * nbn (bm>=98 pad blocks exit)
    gemm_kernel<256><<<8 * 13 * 9, 256, 0, stream>>>(xbf, wbf, 768, 0, qb, vb, qws, kws, vtws, nullptr, nullptr);
    // one block per bh (8 waves); b-affine XCD map (x owns batches 8x..8x+7)
    attn_kernel<<<768, 512, 0, stream>>>(qws, kws, vtws, rpbm, aout);
    // proj: BN=128 -> 624 blocks, 3 blocks/CU (fully resident in one round)
    gemm_kernel<128><<<8 * 13 * 6, 256, 0, stream>>>(aout, pwbf, 768, 1, nullptr, nullptr, nullptr, nullptr, nullptr, pb, out);
}

// Round 19
// 146.779 us; speedup vs baseline: 1.0279x; 1.0279x over previous
//
#include <hip/hip_runtime.h>
#include <hip/hip_bf16.h>
#include <stdint.h>

typedef __attribute__((ext_vector_type(8))) short bf16x8_t;
typedef __attribute__((ext_vector_type(4))) float f32x4_t;
typedef unsigned int u32;
typedef unsigned short u16;
typedef u32 __attribute__((address_space(3))) lds_u32;
typedef u32 __attribute__((address_space(1))) gbl_u32;

#define NUM_H 12
#define NTOK 196
#define NBATCH 64
#define CDIM 768
#define VTS 224    // V^T global token stride
#define VLS 232    // V^T LDS token stride (bank-friendly)
#define RPS 208    // rpb transposed pad (cols and qr)
#define LOG2E 1.44269504f

__device__ __forceinline__ u16 f2bf(float f) {
    u32 u = __float_as_uint(f);
    u32 r = u + 0x7FFFu + ((u >> 16) & 1u);
    return (u16)(r >> 16);
}

// ---- prep: fp32->bf16 convert (3 arrays) + rpb expand, one launch ----
// r19: rpb store decode swapped so qr is the fast axis across threads ->
// consecutive lanes store +4B (coalesced); r18's layout stored at stride 832B
// (12 scattered 4B stores/thread, ~line-amplified writes of a 2MB table).
__global__ void prep_kernel(const float* __restrict__ a, u16* __restrict__ oa, int na4,
                            const float* __restrict__ b, u16* __restrict__ ob, int nb4,
                            const float* __restrict__ c, u16* __restrict__ oc, int nc4,
                            const float* __restrict__ table, const int* __restrict__ idx,
                            float* __restrict__ rpbt) {
    // rpb part: [729][12] -> [12][208 col][208 qr], log2-domain, pads -1e30
    int ij = blockIdx.x * 256 + threadIdx.x;
    if (ij < RPS * RPS) {
        const int col = ij / RPS, qr = ij - col * RPS; // qr fast -> coalesced stores
        const bool pad = (qr >= NTOK) | (col >= NTOK);
        const int rp = pad ? 0 : idx[qr * NTOK + col];
        #pragma unroll
        for (int h = 0; h < NUM_H; h++)
            rpbt[((size_t)h * RPS + col) * RPS + qr] =
                pad ? -1e30f : table[rp * NUM_H + h] * LOG2E;
    }
    // cvt part: grid-stride
    const int total = na4 + nb4 + nc4;
    for (int i = blockIdx.x * blockDim.x + threadIdx.x; i < total; i += gridDim.x * blockDim.x) {
        const float* src;
        u16* dst;
        int j = i;
        if (j < na4) { src = a; dst = oa; }
        else if ((j -= na4) < nb4) { src = b; dst = ob; }
        else { j -= nb4; src = c; dst = oc; }
        float4 v = ((const float4*)src)[j];
        ushort4 o;
        o.x = f2bf(v.x); o.y = f2bf(v.y); o.z = f2bf(v.z); o.w = f2bf(v.w);
        ((ushort4*)dst)[j] = o;
    }
}

// ---------------- GEMM: C[M,N] = A[M,K] @ W[N,K]^T  (bf16 in, epilogue per mode) ----
// r16 body (best measured): single-phase K-step, triple-buffered LDS, counted
// vmcnt, 2-ahead DMA, setprio around the MFMA cluster.
// BN=256: QKV (72KB, 2 blk/CU, vmcnt(6)). BN=128: proj (48KB, 3 blk/CU, vmcnt(4)).
template <int BN>
__global__ __launch_bounds__(256, BN == 256 ? 2 : 3) void gemm_kernel(
    const u16* __restrict__ A, const u16* __restrict__ W, int K, int mode,
    const float* __restrict__ bias_q, const float* __restrict__ bias_v,
    u16* __restrict__ oq, u16* __restrict__ ok, u16* __restrict__ ovt,
    const float* __restrict__ pbias, float* __restrict__ of) {
    constexpr int NBT = BN / 32;        // n-tiles (16 wide) per wave
    constexpr int BOFF = 4096;          // A area in u16
    __shared__ __align__(16) u16 lds[3][BOFF + BN * 32];
    const int tid = threadIdx.x;
    const int wave = tid >> 6, lane = tid & 63;
    const int wr = wave >> 1, wc = wave & 1; // 2x2 wave grid
    const int bid = blockIdx.x;
    const int xcd = bid & 7, i = bid >> 3;
    const int i13 = i / 13;
    const int bm = xcd * 13 + (i - i13 * 13);
    const int bn = i13;
    if (bm >= 98) return; // pad blocks (uniform per block, before any barrier)

    f32x4_t acc[4][NBT];
    #pragma unroll
    for (int ii = 0; ii < 4; ii++)
        #pragma unroll
        for (int jj = 0; jj < NBT; jj++) acc[ii][jj] = f32x4_t{0.f, 0.f, 0.f, 0.f};

    auto stage = [&](int buf, int kt) {
        const int k0 = kt * 32;
        const int su = (lane & 3) ^ ((lane >> 2) & 3) ^ ((lane >> 4) & 3);
        // A: 8 chunks of 16 rows (2 per wave)
        #pragma unroll
        for (int c2 = 0; c2 < 2; c2++) {
            const int c = wave * 2 + c2;
            const int row = bm * 128 + c * 16 + (lane >> 2);
            const u16* src = A + (size_t)row * K + k0 + su * 8;
            __builtin_amdgcn_global_load_lds((gbl_u32*)src, (lds_u32*)&lds[buf][c * 512], 16, 0, 0);
        }
        // B: BN/16 chunks of 16 rows (BN/64 per wave)
        #pragma unroll
        for (int c2 = 0; c2 < BN / 64; c2++) {
            const int c = wave * (BN / 64) + c2;
            const int row = bn * BN + c * 16 + (lane >> 2);
            const u16* src = W + (size_t)row * K + k0 + su * 8;
            __builtin_amdgcn_global_load_lds((gbl_u32*)src, (lds_u32*)&lds[buf][BOFF + c * 512], 16, 0, 0);
        }
    };

    const int NKT = K >> 5; // 24
    stage(0, 0);
    if (NKT > 1) stage(1, 1);
    #pragma unroll 3
    for (int kt = 0; kt < NKT; ++kt) {
        const int buf = kt % 3;
        if (kt + 1 < NKT) {
            if constexpr (BN == 256) asm volatile("s_waitcnt vmcnt(6)" ::: "memory");
            else                     asm volatile("s_waitcnt vmcnt(4)" ::: "memory");
        } else {
            asm volatile("s_waitcnt vmcnt(0)" ::: "memory");
        }
        __builtin_amdgcn_s_barrier();
        if (kt + 2 < NKT) stage((kt + 2) % 3, kt + 2); // DMA overlaps compute below
        bf16x8_t af[4], bfr[NBT];
        #pragma unroll
        for (int mt = 0; mt < 4; mt++) {
            const int r = wr * 64 + mt * 16 + (lane & 15);
            const int u = (lane >> 4) ^ (r & 3) ^ ((r >> 2) & 3);
            af[mt] = *(const bf16x8_t*)&lds[buf][r * 32 + u * 8];
        }
        #pragma unroll
        for (int nt = 0; nt < NBT; nt++) {
            const int r = wc * (BN / 2) + nt * 16 + (lane & 15);
            const int u = (lane >> 4) ^ (r & 3) ^ ((r >> 2) & 3);
            bfr[nt] = *(const bf16x8_t*)&lds[buf][BOFF + r * 32 + u * 8];
        }
        __builtin_amdgcn_s_setprio(1);
        #pragma unroll
        for (int mt = 0; mt < 4; mt++)
            #pragma unroll
            for (int nt = 0; nt < NBT; nt++)
                acc[mt][nt] = __builtin_amdgcn_mfma_f32_16x16x32_bf16(af[mt], bfr[nt], acc[mt][nt], 0, 0, 0);
        __builtin_amdgcn_s_setprio(0);
    }

    const int g = lane >> 4, lc = lane & 15;
    if (mode == 0) {
        if constexpr (BN == 256) {
            const int n_base = bn * 256 + wc * 128; // single qkv region (768 = 3*256)
            const int which = n_base / CDIM;
            const int rem0 = n_base - which * CDIM;
            if (which == 2) {
                #pragma unroll
                for (int nt = 0; nt < 8; nt++) {
                    const int rem = rem0 + nt * 16 + lc;
                    const int hh = rem >> 6, d = rem & 63;
                    const float bias = bias_v[rem];
                    #pragma unroll
                    for (int mt = 0; mt < 4; mt++) {
                        const int m0 = bm * 128 + wr * 64 + mt * 16 + 4 * g;
                        const int bb = m0 / NTOK, t0 = m0 - bb * NTOK; // r=0..3 in-row (196%4==0)
                        ushort4 vv;
                        vv.x = f2bf(acc[mt][nt][0] + bias);
                        vv.y = f2bf(acc[mt][nt][1] + bias);
                        vv.z = f2bf(acc[mt][nt][2] + bias);
                        vv.w = f2bf(acc[mt][nt][3] + bias);
                        *(ushort4*)&ovt[(((size_t)bb * NUM_H + hh) * 64 + d) * VTS + t0] = vv;
                    }
                }
            } else {
                // q/k: LDS-bounce wave's 64x128 tile, then 16 coalesced bf16x8 stores.
                __builtin_amdgcn_s_barrier(); // bounce area overlaps K-loop bufs
                u16* tile = ((u16*)lds) + wave * 8192; // 16KB per wave
                const float scale = (which == 0) ? 0.125f * LOG2E : 1.f;
                #pragma unroll
                for (int nt = 0; nt < 8; nt++) {
                    const int rem = rem0 + nt * 16 + lc;
                    const float bias = (which == 0) ? bias_q[rem] : 0.f;
                    const int nl = nt * 16 + lc;
                    #pragma unroll
                    for (int mt = 0; mt < 4; mt++) {
                        #pragma unroll
                        for (int r = 0; r < 4; r++) {
                            const int ml = mt * 16 + 4 * g + r;
                            const int nsw = (nl & 7) | ((((nl >> 3) ^ (ml & 15)) & 15) << 3);
                            tile[ml * 128 + nsw] = f2bf((acc[mt][nt][r] + bias) * scale);
                        }
                    }
                }
                asm volatile("s_waitcnt lgkmcnt(0)" ::: "memory");
                u16* dst = (which == 0) ? oq : ok;
                const int hh0 = rem0 >> 6;
                #pragma unroll
                for (int it = 0; it < 16; it++) {
                    const int ml = it * 4 + (lane >> 4);
                    const int u = lane & 15;
                    const int usw = u ^ (ml & 15);
                    bf16x8_t v = *(const bf16x8_t*)&tile[ml * 128 + usw * 8];
                    const int mg = bm * 128 + wr * 64 + ml;
                    const int bb = mg / NTOK, t = mg - bb * NTOK;
                    const int hh = hh0 + (u >> 3), d0 = (u & 7) * 8;
                    *(bf16x8_t*)&dst[(((size_t)bb * NUM_H + hh) * NTOK + t) * 64 + d0] = v;
                }
            }
        }
    } else {
        #pragma unroll
        for (int mt = 0; mt < 4; mt++) {
            #pragma unroll
            for (int r = 0; r < 4; r++) {
                const int m = bm * 128 + wr * 64 + mt * 16 + 4 * g + r;
                #pragma unroll
                for (int nt = 0; nt < NBT; nt++) {
                    const int n = bn * BN + wc * (BN / 2) + nt * 16 + lc;
                    of[(size_t)m * CDIM + n] = acc[mt][nt][r] + pbias[n];
                }
            }
        }
    }
}

// ---------------- attention: one block per (b,h); K+V^T DMA-staged in LDS ----------
// r16 form (best measured): 4 waves, b-affine XCD map, maskless exp2-domain
// softmax, split K/V vmcnt wait, rpb register-hoist.
__global__ __launch_bounds__(256, 2) void attn_kernel(
    const u16* __restrict__ Q, const u16* __restrict__ Kg, const u16* __restrict__ Vt,
    const float* __restrict__ rpbt, u16* __restrict__ O) {
    __shared__ __align__(16) u16 Ks[208 * 64];   // 26624 B, swizzled rows
    __shared__ __align__(16) u16 Vs[64 * VLS];   // 29696 B = 29 chunks
    __shared__ __align__(16) u16 Ps[4][16 * 64]; // per-wave P transpose buffer
    const int lane = threadIdx.x & 63, wave = threadIdx.x >> 6;
    const int x = blockIdx.x & 7, j = blockIdx.x >> 3;
    const int j12 = j / 12;
    const int b = 8 * x + j12;
    const int h = j - 12 * j12;
    const int bh = b * NUM_H + h;
    const u16* Qb = Q + (size_t)bh * NTOK * 64;
    const u16* Kb = Kg + (size_t)bh * NTOK * 64;
    const u16* Vgb = Vt + (size_t)bh * 64 * VTS;
    const int g = lane >> 4, lc = lane & 15;

    for (int c = wave; c < 26 + 29; c += 4) {
        if (c < 26) {
            const int row = c * 8 + (lane >> 3);
            const int u = lane & 7;
            const int srow = (row < NTOK) ? row : (NTOK - 1);
            const u16* src = Kb + srow * 64 + ((u ^ (row & 7)) << 3);
            __builtin_amdgcn_global_load_lds((gbl_u32*)src, (lds_u32*)&Ks[c * 512], 16, 0, 0);
        } else {
            const int p = (c - 26) * 1024 + lane * 16;
            const int d = p / (VLS * 2);
            const int off = p - d * (VLS * 2);
            const u16* src = (off < VTS * 2) ? (Vgb + d * VTS + (off >> 1)) : Vgb;
            __builtin_amdgcn_global_load_lds((gbl_u32*)src, (lds_u32*)((char*)Vs + (c - 26) * 1024), 16, 0, 0);
        }
    }
    if (wave == 2) asm volatile("s_waitcnt vmcnt(8)" ::: "memory");
    else           asm volatile("s_waitcnt vmcnt(7)" ::: "memory");
    __builtin_amdgcn_s_barrier(); // all waves' K resident; V still in flight

    bool vpending = true;
    for (int qt = wave; qt < 13; qt += 4) {
        const float* rpbc = rpbt + ((size_t)h * RPS + lc) * RPS + qt * 16 + 4 * g;
        bf16x8_t qf[2];
        const int qrow_f = qt * 16 + lc;
        #pragma unroll
        for (int kk = 0; kk < 2; kk++) {
            if (qrow_f < NTOK) qf[kk] = *(const bf16x8_t*)(Qb + qrow_f * 64 + kk * 32 + g * 8);
            else qf[kk] = bf16x8_t{0, 0, 0, 0, 0, 0, 0, 0};
        }
        float4 rp13[13];
        #pragma unroll
        for (int nt = 0; nt < 13; nt++) rp13[nt] = *(const float4*)(rpbc + nt * 16 * RPS);
        f32x4_t s[13];
        #pragma unroll
        for (int nt = 0; nt < 13; nt++) s[nt] = f32x4_t{0.f, 0.f, 0.f, 0.f};
        #pragma unroll
        for (int nt = 0; nt < 13; nt++) {
            #pragma unroll
            for (int kk = 0; kk < 2; kk++) {
                const int kr = nt * 16 + lc;
                const int u = (kk * 4 + g) ^ (kr & 7);
                bf16x8_t kf = *(const bf16x8_t*)&Ks[kr * 64 + u * 8];
                s[nt] = __builtin_amdgcn_mfma_f32_16x16x32_bf16(qf[kk], kf, s[nt], 0, 0, 0);
            }
        }
        float mx[4] = {-3e38f, -3e38f, -3e38f, -3e38f};
        #pragma unroll
        for (int nt = 0; nt < 13; nt++) {
            const float rpv[4] = {rp13[nt].x, rp13[nt].y, rp13[nt].z, rp13[nt].w};
            #pragma unroll
            for (int r = 0; r < 4; r++) {
                const float v = s[nt][r] + rpv[r];
                s[nt][r] = v;
                mx[r] = fmaxf(mx[r], v);
            }
        }
        #pragma unroll
        for (int r = 0; r < 4; r++) {
            mx[r] = fmaxf(mx[r], __shfl_xor(mx[r], 1));
            mx[r] = fmaxf(mx[r], __shfl_xor(mx[r], 2));
            mx[r] = fmaxf(mx[r], __shfl_xor(mx[r], 4));
            mx[r] = fmaxf(mx[r], __shfl_xor(mx[r], 8));
        }
        float sm[4] = {0.f, 0.f, 0.f, 0.f};
        #pragma unroll
        for (int nt = 0; nt < 13; nt++)
            #pragma unroll
            for (int r = 0; r < 4; r++) {
                float p = exp2f(s[nt][r] - mx[r]);
                s[nt][r] = p;
                sm[r] += p;
            }
        float inv[4];
        #pragma unroll
        for (int r = 0; r < 4; r++) {
            sm[r] += __shfl_xor(sm[r], 1);
            sm[r] += __shfl_xor(sm[r], 2);
            sm[r] += __shfl_xor(sm[r], 4);
            sm[r] += __shfl_xor(sm[r], 8);
            inv[r] = 1.f / sm[r];
        }

        if (vpending) {
            asm volatile("s_waitcnt vmcnt(0)" ::: "memory");
            __builtin_amdgcn_s_barrier();
            vpending = false;
        }

        f32x4_t o4[4];
        #pragma unroll
        for (int dt = 0; dt < 4; dt++) o4[dt] = f32x4_t{0.f, 0.f, 0.f, 0.f};
        for (int kc = 0; kc < 4; kc++) {
            #pragma unroll
            for (int ntl = 0; ntl < 4; ntl++) {
                const int nt = kc * 4 + ntl;
                const int kl = ntl * 16 + lc;
                #pragma unroll
                for (int r = 0; r < 4; r++) {
                    const int rr = 4 * g + r;
                    u16 pv = 0;
                    if (nt < 13) pv = f2bf(s[nt][r]);
                    Ps[wave][rr * 64 + (((kl >> 3) ^ (rr & 7)) << 3) + (kl & 7)] = pv;
                }
            }
            asm volatile("s_waitcnt lgkmcnt(0)" ::: "memory");
            const int nsteps = (kc < 3) ? 2 : 1;
            for (int ks = 0; ks < nsteps; ks++) {
                const int rr = lc;
                const int u = (ks * 4 + g) ^ (rr & 7);
                bf16x8_t pf = *(const bf16x8_t*)&Ps[wave][rr * 64 + u * 8];
                #pragma unroll
                for (int dt = 0; dt < 4; dt++) {
                    const int dcol = dt * 16 + lc;
                    const int kb = kc * 64 + ks * 32 + g * 8;
                    bf16x8_t vf = *(const bf16x8_t*)&Vs[dcol * VLS + kb];
                    o4[dt] = __builtin_amdgcn_mfma_f32_16x16x32_bf16(pf, vf, o4[dt], 0, 0, 0);
                }
            }
            asm volatile("" ::: "memory");
        }
        #pragma unroll
        for (int dt = 0; dt < 4; dt++)
            #pragma unroll
            for (int r = 0; r < 4; r++) {
                const int qr = qt * 16 + 4 * g + r;
                if (qr < NTOK)
                    O[((size_t)b * NTOK + qr) * CDIM + h * 64 + dt * 16 + lc] = f2bf(o4[dt][r] * inv[r]);
            }
    }
}

extern "C" void kernel_launch(void* const* d_in, const int* in_sizes, int n_in,
                              void* d_out, int out_size, void* d_ws, size_t ws_size,
                              hipStream_t stream) {
    const float* x = (const float*)d_in[0];
    const float* qkvw = (const float*)d_in[1];
    const float* qb = (const float*)d_in[2];
    const float* vb = (const float*)d_in[3];
    const float* rpbt = (const float*)d_in[4];
    const int* rpi = (const int*)d_in[5];
    const float* pw = (const float*)d_in[6];
    const float* pb = (const float*)d_in[7];
    float* out = (float*)d_out;

    char* ws = (char*)d_ws;
    size_t off = 0;
    auto alloc = [&](size_t bytes) {
        void* p = ws + off;
        off += (bytes + 255) & ~(size_t)255;
        return p;
    };
    const size_t MROWS = 12544; // 64*196
    u16* xbf = (u16*)alloc(MROWS * 768 * 2);
    u16* wbf = (u16*)alloc((size_t)2304 * 768 * 2);
    u16* pwbf = (u16*)alloc((size_t)768 * 768 * 2);
    u16* qws = (u16*)alloc(MROWS * 768 * 2);
    u16* kws = (u16*)alloc(MROWS * 768 * 2);
    u16* vtws = (u16*)alloc((size_t)768 * 64 * VTS * 2 + 256); // V^T [bh][64][VTS] (+slack)
    u16* aout = (u16*)alloc(MROWS * 768 * 2);
    float* rpbm = (float*)alloc((size_t)NUM_H * RPS * RPS * 4 + 256); // [h][col][qr], log2-domain, pads -1e30

    prep_kernel<<<2048, 256, 0, stream>>>(x, xbf, (12544 * 768) / 4,
                                          qkvw, wbf, (2304 * 768) / 4,
                                          pw, pwbf, (768 * 768) / 4,
                                          rpbt, rpi, rpbm);
    // XCD-swizzled 1D grids: 8 XCDs * 13 bm-strip * nbn (bm>=98 pad blocks exit)
    gemm_kernel<256><<<8 * 13 * 9, 256, 0, stream>>>(xbf, wbf, 768, 0, qb, vb, qws, kws, vtws, nullptr, nullptr);
    // one block per bh; b-affine XCD map (x owns batches 8x..8x+7)
    attn_kernel<<<768, 256, 0, stream>>>(qws, kws, vtws, rpbm, aout);
    // proj: BN=128 -> 624 blocks, 3 blocks/CU (fully resident in one round)
    gemm_kernel<128><<<8 * 13 * 6, 256, 0, stream>>>(aout, pwbf, 768, 1, nullptr, nullptr, nullptr, nullptr, nullptr, pb, out);
}